// Round 2
// baseline (1451.864 us; speedup 1.0000x reference)
//
#include <hip/hip_runtime.h>

#define N_NODES 100000
#define N_EDGES 1600000
#define NFEAT 64
#define NCLASS 64

// ---------------------------------------------------------------------------
// Kernel 1: zero the aggregation buffer (d_out doubles as agg storage).
// ---------------------------------------------------------------------------
__global__ void zero_kernel(float4* __restrict__ p, int n4) {
    int i = blockIdx.x * blockDim.x + threadIdx.x;
    int stride = gridDim.x * blockDim.x;
    for (; i < n4; i += stride) p[i] = make_float4(0.f, 0.f, 0.f, 0.f);
}

// ---------------------------------------------------------------------------
// Kernel 2: edge scatter-add.  16 lanes per edge, float4 per lane.
// agg[dst[e]][:] += x[src[e]][:]
// NOTE: harness delivers integer inputs as int32 regardless of reference int64.
// ---------------------------------------------------------------------------
__global__ void scatter_kernel(const float4* __restrict__ x4,
                               const int* __restrict__ src,
                               const int* __restrict__ dst,
                               float* __restrict__ agg) {
    int idx = blockIdx.x * blockDim.x + threadIdx.x;
    const int total = N_EDGES * 16;           // 25.6M threads-of-work
    int stride = gridDim.x * blockDim.x;
    for (; idx < total; idx += stride) {
        int e = idx >> 4;
        int q = idx & 15;                      // which float4 of the row
        int s = src[e];
        int d = dst[e];
        float4 v = x4[s * 16 + q];
        float* base = agg + d * 64 + q * 4;
        unsafeAtomicAdd(base + 0, v.x);
        unsafeAtomicAdd(base + 1, v.y);
        unsafeAtomicAdd(base + 2, v.z);
        unsafeAtomicAdd(base + 3, v.w);
    }
}

// ---------------------------------------------------------------------------
// Kernel 3: per-node transform, in place on d_out.
// out[i][c] = relu( sum_f agg[i][f]*W_rel[c][f] + b[c] + sum_f x[i][f]*W_root[c][f] )
// Weights staged TRANSPOSED in LDS (wt[f][c], row padded to 65 floats):
// 64 lanes read consecutive c -> conflict-free; agg/x row reads are broadcast.
// ---------------------------------------------------------------------------
__global__ __launch_bounds__(256) void transform_kernel(
    const float* __restrict__ x,
    const float* __restrict__ W_rel,    // [class][feat] row-major
    const float* __restrict__ b_rel,
    const float* __restrict__ W_root,
    float* __restrict__ agg_out) {      // in: agg, out: result (in-place)
    __shared__ float wrel[NFEAT][NCLASS + 1];
    __shared__ float wroot[NFEAT][NCLASS + 1];
    __shared__ float bsh[NCLASS];
    __shared__ float aggrow[4][NFEAT];
    __shared__ float xrow[4][NFEAT];

    const int tid = threadIdx.x;
    for (int i = tid; i < NFEAT * NCLASS; i += 256) {
        int c = i >> 6, f = i & 63;
        wrel[f][c]  = W_rel[i];     // global read coalesced; LDS write conflicts
        wroot[f][c] = W_root[i];    // are one-time-per-block, negligible
    }
    if (tid < NCLASS) bsh[tid] = b_rel[tid];

    const int nsub = tid >> 6;   // 0..3: which node of the 4-node group
    const int c    = tid & 63;   // class

    for (int nb = blockIdx.x * 4; nb < N_NODES; nb += gridDim.x * 4) {
        __syncthreads();   // protect LDS rows from previous iteration's readers
        for (int i = tid; i < 4 * NFEAT; i += 256) {
            int r = i >> 6, f = i & 63;
            int node = nb + r;
            if (node < N_NODES) {
                aggrow[r][f] = agg_out[node * 64 + f];
                xrow[r][f]   = x[node * 64 + f];
            }
        }
        __syncthreads();
        int node = nb + nsub;
        if (node < N_NODES) {
            float acc = bsh[c];
            #pragma unroll
            for (int f = 0; f < NFEAT; ++f) {
                acc += aggrow[nsub][f] * wrel[f][c];
                acc += xrow[nsub][f]   * wroot[f][c];
            }
            agg_out[node * 64 + c] = fmaxf(acc, 0.f);
        }
    }
}

extern "C" void kernel_launch(void* const* d_in, const int* in_sizes, int n_in,
                              void* d_out, int out_size, void* d_ws, size_t ws_size,
                              hipStream_t stream) {
    const float* x      = (const float*)d_in[0];
    const int*   adj    = (const int*)d_in[1];   // delivered as int32 [2][N_EDGES]
    const float* W_rel  = (const float*)d_in[2];
    const float* b_rel  = (const float*)d_in[3];
    const float* W_root = (const float*)d_in[4];
    float*       out    = (float*)d_out;

    const int* src = adj;
    const int* dst = adj + N_EDGES;

    zero_kernel<<<2048, 256, 0, stream>>>((float4*)out, (N_NODES * NFEAT) / 4);
    scatter_kernel<<<4096, 256, 0, stream>>>((const float4*)x, src, dst, out);
    transform_kernel<<<2048, 256, 0, stream>>>(x, W_rel, b_rel, W_root, out);
}

// Round 3
// 562.014 us; speedup vs baseline: 2.5833x; 2.5833x over previous
//
#include <hip/hip_runtime.h>

#define N_NODES 100000
#define N_EDGES 1600000
#define NFEAT 64
#define NCLASS 64

// ---------------------------------------------------------------------------
// CSR-build kernels (counting sort by destination)
// ---------------------------------------------------------------------------
__global__ void zero_int_kernel(int* __restrict__ p, int n) {
    int i = blockIdx.x * blockDim.x + threadIdx.x;
    int stride = gridDim.x * blockDim.x;
    for (; i < n; i += stride) p[i] = 0;
}

__global__ void hist_kernel(const int* __restrict__ dst, int* __restrict__ deg) {
    int e = blockIdx.x * blockDim.x + threadIdx.x;
    int stride = gridDim.x * blockDim.x;
    for (; e < N_EDGES; e += stride) atomicAdd(&deg[dst[e]], 1);
}

#define SCAN_T 1024
__global__ __launch_bounds__(SCAN_T) void scan_kernel(const int* __restrict__ deg,
                                                      int* __restrict__ offs,
                                                      int* __restrict__ cursor) {
    __shared__ int part[SCAN_T];
    const int C = (N_NODES + SCAN_T - 1) / SCAN_T;   // 98 elems/thread
    int t = threadIdx.x;
    int beg = t * C;
    int end = min(beg + C, N_NODES);
    int s = 0;
    for (int i = beg; i < end; ++i) s += deg[i];
    part[t] = s;
    __syncthreads();
    // Hillis-Steele inclusive scan over the 1024 partials
    for (int off = 1; off < SCAN_T; off <<= 1) {
        int v = (t >= off) ? part[t - off] : 0;
        __syncthreads();
        part[t] += v;
        __syncthreads();
    }
    int run = (t > 0) ? part[t - 1] : 0;  // exclusive prefix of this chunk
    for (int i = beg; i < end; ++i) {
        offs[i] = run;
        cursor[i] = run;
        run += deg[i];
    }
    if (t == SCAN_T - 1) offs[N_NODES] = part[SCAN_T - 1];
}

__global__ void fill_kernel(const int* __restrict__ src, const int* __restrict__ dst,
                            int* __restrict__ cursor, int* __restrict__ srclist) {
    int e = blockIdx.x * blockDim.x + threadIdx.x;
    int stride = gridDim.x * blockDim.x;
    for (; e < N_EDGES; e += stride) {
        int p = atomicAdd(&cursor[dst[e]], 1);
        srclist[p] = src[e];
    }
}

// ---------------------------------------------------------------------------
// Gather aggregation: one 64-lane wave per node, lane = feature.
// agg[i][lane] = sum_{j in nbrs(i)} x[j][lane]   (coalesced 256B row reads)
// ---------------------------------------------------------------------------
__global__ __launch_bounds__(256) void gather_kernel(const float* __restrict__ x,
                                                     const int* __restrict__ offs,
                                                     const int* __restrict__ srclist,
                                                     float* __restrict__ agg) {
    int wave = (blockIdx.x * blockDim.x + threadIdx.x) >> 6;
    int lane = threadIdx.x & 63;
    if (wave >= N_NODES) return;
    int beg = offs[wave];
    int end = offs[wave + 1];
    float acc = 0.f;
    int j = beg;
    for (; j + 4 <= end; j += 4) {           // unroll 4: independent loads in flight
        int s0 = srclist[j + 0];
        int s1 = srclist[j + 1];
        int s2 = srclist[j + 2];
        int s3 = srclist[j + 3];
        float v0 = x[s0 * 64 + lane];
        float v1 = x[s1 * 64 + lane];
        float v2 = x[s2 * 64 + lane];
        float v3 = x[s3 * 64 + lane];
        acc += v0; acc += v1; acc += v2; acc += v3;
    }
    for (; j < end; ++j) acc += x[srclist[j] * 64 + lane];
    agg[wave * 64 + lane] = acc;
}

// ---------------------------------------------------------------------------
// Fallback path (round-2 proven): atomic scatter
// ---------------------------------------------------------------------------
__global__ void zero_kernel(float4* __restrict__ p, int n4) {
    int i = blockIdx.x * blockDim.x + threadIdx.x;
    int stride = gridDim.x * blockDim.x;
    for (; i < n4; i += stride) p[i] = make_float4(0.f, 0.f, 0.f, 0.f);
}

__global__ void scatter_kernel(const float4* __restrict__ x4,
                               const int* __restrict__ src,
                               const int* __restrict__ dst,
                               float* __restrict__ agg) {
    int idx = blockIdx.x * blockDim.x + threadIdx.x;
    const int total = N_EDGES * 16;
    int stride = gridDim.x * blockDim.x;
    for (; idx < total; idx += stride) {
        int e = idx >> 4;
        int q = idx & 15;
        int s = src[e];
        int d = dst[e];
        float4 v = x4[s * 16 + q];
        float* base = agg + d * 64 + q * 4;
        unsafeAtomicAdd(base + 0, v.x);
        unsafeAtomicAdd(base + 1, v.y);
        unsafeAtomicAdd(base + 2, v.z);
        unsafeAtomicAdd(base + 3, v.w);
    }
}

// ---------------------------------------------------------------------------
// Per-node transform, in place on d_out (agg -> relu(lin_rel(agg)+lin_root(x)))
// ---------------------------------------------------------------------------
__global__ __launch_bounds__(256) void transform_kernel(
    const float* __restrict__ x,
    const float* __restrict__ W_rel,    // [class][feat] row-major
    const float* __restrict__ b_rel,
    const float* __restrict__ W_root,
    float* __restrict__ agg_out) {
    __shared__ float wrel[NFEAT][NCLASS + 1];
    __shared__ float wroot[NFEAT][NCLASS + 1];
    __shared__ float bsh[NCLASS];
    __shared__ float aggrow[4][NFEAT];
    __shared__ float xrow[4][NFEAT];

    const int tid = threadIdx.x;
    for (int i = tid; i < NFEAT * NCLASS; i += 256) {
        int c = i >> 6, f = i & 63;
        wrel[f][c]  = W_rel[i];
        wroot[f][c] = W_root[i];
    }
    if (tid < NCLASS) bsh[tid] = b_rel[tid];

    const int nsub = tid >> 6;
    const int c    = tid & 63;

    for (int nb = blockIdx.x * 4; nb < N_NODES; nb += gridDim.x * 4) {
        __syncthreads();
        for (int i = tid; i < 4 * NFEAT; i += 256) {
            int r = i >> 6, f = i & 63;
            int node = nb + r;
            if (node < N_NODES) {
                aggrow[r][f] = agg_out[node * 64 + f];
                xrow[r][f]   = x[node * 64 + f];
            }
        }
        __syncthreads();
        int node = nb + nsub;
        if (node < N_NODES) {
            float acc = bsh[c];
            #pragma unroll
            for (int f = 0; f < NFEAT; ++f) {
                acc += aggrow[nsub][f] * wrel[f][c];
                acc += xrow[nsub][f]   * wroot[f][c];
            }
            agg_out[node * 64 + c] = fmaxf(acc, 0.f);
        }
    }
}

extern "C" void kernel_launch(void* const* d_in, const int* in_sizes, int n_in,
                              void* d_out, int out_size, void* d_ws, size_t ws_size,
                              hipStream_t stream) {
    const float* x      = (const float*)d_in[0];
    const int*   adj    = (const int*)d_in[1];   // delivered as int32 [2][N_EDGES]
    const float* W_rel  = (const float*)d_in[2];
    const float* b_rel  = (const float*)d_in[3];
    const float* W_root = (const float*)d_in[4];
    float*       out    = (float*)d_out;

    const int* src = adj;
    const int* dst = adj + N_EDGES;

    // workspace layout (ints, 128-elem aligned blocks)
    const size_t NPAD = 100032;                 // >= N_NODES+1, multiple of 64
    const size_t ws_needed = (3 * NPAD + (size_t)N_EDGES) * sizeof(int);

    if (ws_size >= ws_needed) {
        int* deg     = (int*)d_ws;
        int* offs    = deg + NPAD;
        int* cursor  = offs + NPAD;
        int* srclist = cursor + NPAD;

        zero_int_kernel<<<128, 256, 0, stream>>>(deg, N_NODES);
        hist_kernel<<<2048, 256, 0, stream>>>(dst, deg);
        scan_kernel<<<1, SCAN_T, 0, stream>>>(deg, offs, cursor);
        fill_kernel<<<2048, 256, 0, stream>>>(src, dst, cursor, srclist);
        gather_kernel<<<(N_NODES * 64 + 255) / 256, 256, 0, stream>>>(x, offs, srclist, out);
    } else {
        // fallback: atomic scatter (proven round 2)
        zero_kernel<<<2048, 256, 0, stream>>>((float4*)out, (N_NODES * NFEAT) / 4);
        scatter_kernel<<<4096, 256, 0, stream>>>((const float4*)x, src, dst, out);
    }
    transform_kernel<<<2048, 256, 0, stream>>>(x, W_rel, b_rel, W_root, out);
}

// Round 4
// 361.733 us; speedup vs baseline: 4.0136x; 1.5537x over previous
//
#include <hip/hip_runtime.h>

#define N_NODES 100000
#define N_EDGES 1600000
#define NFEAT 64
#define NCLASS 64

// ---------------------------------------------------------------------------
// CSR-build kernels (counting sort by destination)
// ---------------------------------------------------------------------------
__global__ void zero_int_kernel(int* __restrict__ p, int n) {
    int i = blockIdx.x * blockDim.x + threadIdx.x;
    int stride = gridDim.x * blockDim.x;
    for (; i < n; i += stride) p[i] = 0;
}

__global__ void hist_kernel(const int* __restrict__ dst, int* __restrict__ deg) {
    int e = blockIdx.x * blockDim.x + threadIdx.x;
    int stride = gridDim.x * blockDim.x;
    for (; e < N_EDGES; e += stride) atomicAdd(&deg[dst[e]], 1);
}

// ---- multi-block exclusive scan of deg[0..N_NODES) -> offs, cursor ----
#define SCAN_CHUNK 512                                   // elems per block
#define SCAN_NBLK ((N_NODES + SCAN_CHUNK - 1) / SCAN_CHUNK)   // 196

__global__ __launch_bounds__(256) void scan1_kernel(const int* __restrict__ deg,
                                                    int* __restrict__ blocksum) {
    __shared__ int part[256];
    int b = blockIdx.x, t = threadIdx.x;
    int i0 = b * SCAN_CHUNK + t * 2;
    int s = 0;
    if (i0 < N_NODES)     s += deg[i0];
    if (i0 + 1 < N_NODES) s += deg[i0 + 1];
    part[t] = s;
    __syncthreads();
    for (int off = 128; off > 0; off >>= 1) {
        if (t < off) part[t] += part[t + off];
        __syncthreads();
    }
    if (t == 0) blocksum[b] = part[0];
}

__global__ __launch_bounds__(256) void scan2_kernel(const int* __restrict__ blocksum,
                                                    int* __restrict__ blockoff,
                                                    int* __restrict__ offs) {
    __shared__ int part[256];
    int t = threadIdx.x;
    int v = (t < SCAN_NBLK) ? blocksum[t] : 0;
    part[t] = v;
    __syncthreads();
    for (int off = 1; off < 256; off <<= 1) {
        int u = (t >= off) ? part[t - off] : 0;
        __syncthreads();
        part[t] += u;
        __syncthreads();
    }
    if (t < SCAN_NBLK) blockoff[t] = part[t] - v;   // exclusive
    if (t == 0) offs[N_NODES] = part[255];          // total edges
}

__global__ __launch_bounds__(256) void scan3_kernel(const int* __restrict__ deg,
                                                    const int* __restrict__ blockoff,
                                                    int* __restrict__ offs,
                                                    int* __restrict__ cursor) {
    __shared__ int part[256];
    int b = blockIdx.x, t = threadIdx.x;
    int i0 = b * SCAN_CHUNK + t * 2;
    int d0 = (i0 < N_NODES) ? deg[i0] : 0;
    int d1 = (i0 + 1 < N_NODES) ? deg[i0 + 1] : 0;
    int p = d0 + d1;
    part[t] = p;
    __syncthreads();
    for (int off = 1; off < 256; off <<= 1) {
        int u = (t >= off) ? part[t - off] : 0;
        __syncthreads();
        part[t] += u;
        __syncthreads();
    }
    int base = blockoff[b] + part[t] - p;            // exclusive prefix
    if (i0 < N_NODES)     { offs[i0] = base;           cursor[i0] = base; }
    if (i0 + 1 < N_NODES) { offs[i0 + 1] = base + d0;  cursor[i0 + 1] = base + d0; }
}

__global__ void fill_kernel(const int* __restrict__ src, const int* __restrict__ dst,
                            int* __restrict__ cursor, int* __restrict__ srclist) {
    int e = blockIdx.x * blockDim.x + threadIdx.x;
    int stride = gridDim.x * blockDim.x;
    for (; e < N_EDGES; e += stride) {
        int p = atomicAdd(&cursor[dst[e]], 1);
        srclist[p] = src[e];
    }
}

// ---------------------------------------------------------------------------
// Gather aggregation: one 64-lane wave per node, lane = feature.
// ---------------------------------------------------------------------------
__global__ __launch_bounds__(256) void gather_kernel(const float* __restrict__ x,
                                                     const int* __restrict__ offs,
                                                     const int* __restrict__ srclist,
                                                     float* __restrict__ agg) {
    int wave = (blockIdx.x * blockDim.x + threadIdx.x) >> 6;
    int lane = threadIdx.x & 63;
    if (wave >= N_NODES) return;
    int beg = offs[wave];
    int end = offs[wave + 1];
    float acc = 0.f;
    int j = beg;
    for (; j + 4 <= end; j += 4) {
        int s0 = srclist[j + 0];
        int s1 = srclist[j + 1];
        int s2 = srclist[j + 2];
        int s3 = srclist[j + 3];
        float v0 = x[s0 * 64 + lane];
        float v1 = x[s1 * 64 + lane];
        float v2 = x[s2 * 64 + lane];
        float v3 = x[s3 * 64 + lane];
        acc += v0; acc += v1; acc += v2; acc += v3;
    }
    for (; j < end; ++j) acc += x[srclist[j] * 64 + lane];
    agg[wave * 64 + lane] = acc;
}

// ---------------------------------------------------------------------------
// Fallback path: atomic scatter (proven round 2)
// ---------------------------------------------------------------------------
__global__ void zero_kernel(float4* __restrict__ p, int n4) {
    int i = blockIdx.x * blockDim.x + threadIdx.x;
    int stride = gridDim.x * blockDim.x;
    for (; i < n4; i += stride) p[i] = make_float4(0.f, 0.f, 0.f, 0.f);
}

__global__ void scatter_kernel(const float4* __restrict__ x4,
                               const int* __restrict__ src,
                               const int* __restrict__ dst,
                               float* __restrict__ agg) {
    int idx = blockIdx.x * blockDim.x + threadIdx.x;
    const int total = N_EDGES * 16;
    int stride = gridDim.x * blockDim.x;
    for (; idx < total; idx += stride) {
        int e = idx >> 4;
        int q = idx & 15;
        int s = src[e];
        int d = dst[e];
        float4 v = x4[s * 16 + q];
        float* base = agg + d * 64 + q * 4;
        unsafeAtomicAdd(base + 0, v.x);
        unsafeAtomicAdd(base + 1, v.y);
        unsafeAtomicAdd(base + 2, v.z);
        unsafeAtomicAdd(base + 3, v.w);
    }
}

// ---------------------------------------------------------------------------
// Per-node transform, in place on d_out (agg -> relu(lin_rel(agg)+lin_root(x)))
// ---------------------------------------------------------------------------
__global__ __launch_bounds__(256) void transform_kernel(
    const float* __restrict__ x,
    const float* __restrict__ W_rel,    // [class][feat] row-major
    const float* __restrict__ b_rel,
    const float* __restrict__ W_root,
    float* __restrict__ agg_out) {
    __shared__ float wrel[NFEAT][NCLASS + 1];
    __shared__ float wroot[NFEAT][NCLASS + 1];
    __shared__ float bsh[NCLASS];
    __shared__ float aggrow[4][NFEAT];
    __shared__ float xrow[4][NFEAT];

    const int tid = threadIdx.x;
    for (int i = tid; i < NFEAT * NCLASS; i += 256) {
        int c = i >> 6, f = i & 63;
        wrel[f][c]  = W_rel[i];
        wroot[f][c] = W_root[i];
    }
    if (tid < NCLASS) bsh[tid] = b_rel[tid];

    const int nsub = tid >> 6;
    const int c    = tid & 63;

    for (int nb = blockIdx.x * 4; nb < N_NODES; nb += gridDim.x * 4) {
        __syncthreads();
        for (int i = tid; i < 4 * NFEAT; i += 256) {
            int r = i >> 6, f = i & 63;
            int node = nb + r;
            if (node < N_NODES) {
                aggrow[r][f] = agg_out[node * 64 + f];
                xrow[r][f]   = x[node * 64 + f];
            }
        }
        __syncthreads();
        int node = nb + nsub;
        if (node < N_NODES) {
            float acc = bsh[c];
            #pragma unroll
            for (int f = 0; f < NFEAT; ++f) {
                acc += aggrow[nsub][f] * wrel[f][c];
                acc += xrow[nsub][f]   * wroot[f][c];
            }
            agg_out[node * 64 + c] = fmaxf(acc, 0.f);
        }
    }
}

extern "C" void kernel_launch(void* const* d_in, const int* in_sizes, int n_in,
                              void* d_out, int out_size, void* d_ws, size_t ws_size,
                              hipStream_t stream) {
    const float* x      = (const float*)d_in[0];
    const int*   adj    = (const int*)d_in[1];   // delivered as int32 [2][N_EDGES]
    const float* W_rel  = (const float*)d_in[2];
    const float* b_rel  = (const float*)d_in[3];
    const float* W_root = (const float*)d_in[4];
    float*       out    = (float*)d_out;

    const int* src = adj;
    const int* dst = adj + N_EDGES;

    // workspace layout (ints)
    const size_t NPAD = 100032;                 // >= N_NODES+1, multiple of 64
    const size_t BPAD = 256;                    // >= SCAN_NBLK, x2 for sum+off
    const size_t ws_needed = (3 * NPAD + 2 * BPAD + (size_t)N_EDGES) * sizeof(int);

    if (ws_size >= ws_needed) {
        int* deg      = (int*)d_ws;
        int* offs     = deg + NPAD;
        int* cursor   = offs + NPAD;
        int* blocksum = cursor + NPAD;
        int* blockoff = blocksum + BPAD;
        int* srclist  = blockoff + BPAD;

        zero_int_kernel<<<128, 256, 0, stream>>>(deg, N_NODES);
        hist_kernel<<<2048, 256, 0, stream>>>(dst, deg);
        scan1_kernel<<<SCAN_NBLK, 256, 0, stream>>>(deg, blocksum);
        scan2_kernel<<<1, 256, 0, stream>>>(blocksum, blockoff, offs);
        scan3_kernel<<<SCAN_NBLK, 256, 0, stream>>>(deg, blockoff, offs, cursor);
        fill_kernel<<<2048, 256, 0, stream>>>(src, dst, cursor, srclist);
        gather_kernel<<<(N_NODES * 64 + 255) / 256, 256, 0, stream>>>(x, offs, srclist, out);
    } else {
        zero_kernel<<<2048, 256, 0, stream>>>((float4*)out, (N_NODES * NFEAT) / 4);
        scatter_kernel<<<4096, 256, 0, stream>>>((const float4*)x, src, dst, out);
    }
    transform_kernel<<<2048, 256, 0, stream>>>(x, W_rel, b_rel, W_root, out);
}

// Round 5
// 359.932 us; speedup vs baseline: 4.0337x; 1.0050x over previous
//
#include <hip/hip_runtime.h>

#define N_NODES 100000
#define N_EDGES 1600000
#define NFEAT 64
#define NCLASS 64
#define NPART 8
#define PART_SZ 12500   // N_NODES / NPART exactly

// ---------------------------------------------------------------------------
// CSR-build kernels (counting sort by destination)
// ---------------------------------------------------------------------------
__global__ void zero_int_kernel(int* __restrict__ p, int n) {
    int i = blockIdx.x * blockDim.x + threadIdx.x;
    int stride = gridDim.x * blockDim.x;
    for (; i < n; i += stride) p[i] = 0;
}

__global__ void hist_kernel(const int* __restrict__ dst, int* __restrict__ deg) {
    int e = blockIdx.x * blockDim.x + threadIdx.x;
    int stride = gridDim.x * blockDim.x;
    for (; e < N_EDGES; e += stride) atomicAdd(&deg[dst[e]], 1);
}

// ---- multi-block exclusive scan of deg[0..N_NODES) -> offs, cursor ----
#define SCAN_CHUNK 512
#define SCAN_NBLK ((N_NODES + SCAN_CHUNK - 1) / SCAN_CHUNK)   // 196

__global__ __launch_bounds__(256) void scan1_kernel(const int* __restrict__ deg,
                                                    int* __restrict__ blocksum) {
    __shared__ int part[256];
    int b = blockIdx.x, t = threadIdx.x;
    int i0 = b * SCAN_CHUNK + t * 2;
    int s = 0;
    if (i0 < N_NODES)     s += deg[i0];
    if (i0 + 1 < N_NODES) s += deg[i0 + 1];
    part[t] = s;
    __syncthreads();
    for (int off = 128; off > 0; off >>= 1) {
        if (t < off) part[t] += part[t + off];
        __syncthreads();
    }
    if (t == 0) blocksum[b] = part[0];
}

__global__ __launch_bounds__(256) void scan2_kernel(const int* __restrict__ blocksum,
                                                    int* __restrict__ blockoff,
                                                    int* __restrict__ offs) {
    __shared__ int part[256];
    int t = threadIdx.x;
    int v = (t < SCAN_NBLK) ? blocksum[t] : 0;
    part[t] = v;
    __syncthreads();
    for (int off = 1; off < 256; off <<= 1) {
        int u = (t >= off) ? part[t - off] : 0;
        __syncthreads();
        part[t] += u;
        __syncthreads();
    }
    if (t < SCAN_NBLK) blockoff[t] = part[t] - v;   // exclusive
    if (t == 0) offs[N_NODES] = part[255];
}

__global__ __launch_bounds__(256) void scan3_kernel(const int* __restrict__ deg,
                                                    const int* __restrict__ blockoff,
                                                    int* __restrict__ offs,
                                                    int* __restrict__ cursor) {
    __shared__ int part[256];
    int b = blockIdx.x, t = threadIdx.x;
    int i0 = b * SCAN_CHUNK + t * 2;
    int d0 = (i0 < N_NODES) ? deg[i0] : 0;
    int d1 = (i0 + 1 < N_NODES) ? deg[i0 + 1] : 0;
    int p = d0 + d1;
    part[t] = p;
    __syncthreads();
    for (int off = 1; off < 256; off <<= 1) {
        int u = (t >= off) ? part[t - off] : 0;
        __syncthreads();
        part[t] += u;
        __syncthreads();
    }
    int base = blockoff[b] + part[t] - p;
    if (i0 < N_NODES)     { offs[i0] = base;           cursor[i0] = base; }
    if (i0 + 1 < N_NODES) { offs[i0 + 1] = base + d0;  cursor[i0 + 1] = base + d0; }
}

// ---------------------------------------------------------------------------
// Partitioned fill: block-group (blockIdx&7) handles dst-part (dst/12500)==g.
// Groups land round-robin on XCDs -> each group's srclist slice (~800KB) stays
// in one XCD's L2; lines written ~16x before a single eviction.
// ---------------------------------------------------------------------------
__global__ __launch_bounds__(256) void fill_part_kernel(const int* __restrict__ src,
                                                        const int* __restrict__ dst,
                                                        int* __restrict__ cursor,
                                                        int* __restrict__ srclist) {
    const int g  = blockIdx.x & (NPART - 1);
    const int gb = blockIdx.x >> 3;                 // block index within group
    const int nb = gridDim.x >> 3;                  // blocks per group
    int e = gb * blockDim.x + threadIdx.x;
    const int stride = nb * blockDim.x;
    for (; e < N_EDGES; e += stride) {
        int d = dst[e];                             // coalesced, L3-resident
        int s = src[e];                             // coalesced, L3-resident
        if (d / PART_SZ == g) {
            int p = atomicAdd(&cursor[d], 1);
            srclist[p] = s;                         // within group's L2-local slice
        }
    }
}

// ---------------------------------------------------------------------------
// Gather aggregation: one 64-lane wave per node, lane = feature.
// ---------------------------------------------------------------------------
__global__ __launch_bounds__(256) void gather_kernel(const float* __restrict__ x,
                                                     const int* __restrict__ offs,
                                                     const int* __restrict__ srclist,
                                                     float* __restrict__ agg) {
    int wave = (blockIdx.x * blockDim.x + threadIdx.x) >> 6;
    int lane = threadIdx.x & 63;
    if (wave >= N_NODES) return;
    int beg = offs[wave];
    int end = offs[wave + 1];
    float acc = 0.f;
    int j = beg;
    for (; j + 4 <= end; j += 4) {
        int s0 = srclist[j + 0];
        int s1 = srclist[j + 1];
        int s2 = srclist[j + 2];
        int s3 = srclist[j + 3];
        float v0 = x[s0 * 64 + lane];
        float v1 = x[s1 * 64 + lane];
        float v2 = x[s2 * 64 + lane];
        float v3 = x[s3 * 64 + lane];
        acc += v0; acc += v1; acc += v2; acc += v3;
    }
    for (; j < end; ++j) acc += x[srclist[j] * 64 + lane];
    agg[wave * 64 + lane] = acc;
}

// ---------------------------------------------------------------------------
// Fallback path: atomic scatter (proven round 2)
// ---------------------------------------------------------------------------
__global__ void zero_kernel(float4* __restrict__ p, int n4) {
    int i = blockIdx.x * blockDim.x + threadIdx.x;
    int stride = gridDim.x * blockDim.x;
    for (; i < n4; i += stride) p[i] = make_float4(0.f, 0.f, 0.f, 0.f);
}

__global__ void scatter_kernel(const float4* __restrict__ x4,
                               const int* __restrict__ src,
                               const int* __restrict__ dst,
                               float* __restrict__ agg) {
    int idx = blockIdx.x * blockDim.x + threadIdx.x;
    const int total = N_EDGES * 16;
    int stride = gridDim.x * blockDim.x;
    for (; idx < total; idx += stride) {
        int e = idx >> 4;
        int q = idx & 15;
        int s = src[e];
        int d = dst[e];
        float4 v = x4[s * 16 + q];
        float* base = agg + d * 64 + q * 4;
        unsafeAtomicAdd(base + 0, v.x);
        unsafeAtomicAdd(base + 1, v.y);
        unsafeAtomicAdd(base + 2, v.z);
        unsafeAtomicAdd(base + 3, v.w);
    }
}

// ---------------------------------------------------------------------------
// Transform v2: lane = class; weight rows live in 128 VGPRs per lane.
// agg/x rows read via wave-uniform float4 loads (hardware line broadcast,
// L2-resident). 128 FMA/node -> VALU-bound. No LDS.
// ---------------------------------------------------------------------------
__global__ __launch_bounds__(256) void transform2_kernel(
    const float* __restrict__ x,
    const float* __restrict__ W_rel,    // [class][feat] row-major
    const float* __restrict__ b_rel,
    const float* __restrict__ W_root,
    float* __restrict__ agg_out) {      // in: agg, out: result (in-place)
    const int lane = threadIdx.x & 63;

    float4 wr[16], wo[16];
    const float4* Wr4 = (const float4*)W_rel;
    const float4* Wo4 = (const float4*)W_root;
    #pragma unroll
    for (int i = 0; i < 16; ++i) {
        wr[i] = Wr4[lane * 16 + i];     // W_rel[lane][4i..4i+3]
        wo[i] = Wo4[lane * 16 + i];
    }
    const float bias = b_rel[lane];

    int gwave = (blockIdx.x * blockDim.x + threadIdx.x) >> 6;
    int nwaves = (gridDim.x * blockDim.x) >> 6;

    for (int node = gwave; node < N_NODES; node += nwaves) {
        const float4* ar4 = (const float4*)(agg_out + (size_t)node * 64);
        const float4* xr4 = (const float4*)(x + (size_t)node * 64);
        float acc = bias;
        #pragma unroll
        for (int i = 0; i < 16; ++i) {
            float4 a = ar4[i];          // wave-uniform address -> broadcast
            float4 v = xr4[i];
            acc += a.x * wr[i].x + a.y * wr[i].y + a.z * wr[i].z + a.w * wr[i].w;
            acc += v.x * wo[i].x + v.y * wo[i].y + v.z * wo[i].z + v.w * wo[i].w;
        }
        agg_out[(size_t)node * 64 + lane] = fmaxf(acc, 0.f);
    }
}

extern "C" void kernel_launch(void* const* d_in, const int* in_sizes, int n_in,
                              void* d_out, int out_size, void* d_ws, size_t ws_size,
                              hipStream_t stream) {
    const float* x      = (const float*)d_in[0];
    const int*   adj    = (const int*)d_in[1];   // delivered as int32 [2][N_EDGES]
    const float* W_rel  = (const float*)d_in[2];
    const float* b_rel  = (const float*)d_in[3];
    const float* W_root = (const float*)d_in[4];
    float*       out    = (float*)d_out;

    const int* src = adj;
    const int* dst = adj + N_EDGES;

    const size_t NPAD = 100032;                 // >= N_NODES+1, multiple of 64
    const size_t BPAD = 256;
    const size_t ws_needed = (3 * NPAD + 2 * BPAD + (size_t)N_EDGES) * sizeof(int);

    if (ws_size >= ws_needed) {
        int* deg      = (int*)d_ws;
        int* offs     = deg + NPAD;
        int* cursor   = offs + NPAD;
        int* blocksum = cursor + NPAD;
        int* blockoff = blocksum + BPAD;
        int* srclist  = blockoff + BPAD;

        zero_int_kernel<<<128, 256, 0, stream>>>(deg, N_NODES);
        hist_kernel<<<2048, 256, 0, stream>>>(dst, deg);
        scan1_kernel<<<SCAN_NBLK, 256, 0, stream>>>(deg, blocksum);
        scan2_kernel<<<1, 256, 0, stream>>>(blocksum, blockoff, offs);
        scan3_kernel<<<SCAN_NBLK, 256, 0, stream>>>(deg, blockoff, offs, cursor);
        fill_part_kernel<<<2048, 256, 0, stream>>>(src, dst, cursor, srclist);
        gather_kernel<<<(N_NODES * 64 + 255) / 256, 256, 0, stream>>>(x, offs, srclist, out);
    } else {
        zero_kernel<<<2048, 256, 0, stream>>>((float4*)out, (N_NODES * NFEAT) / 4);
        scatter_kernel<<<4096, 256, 0, stream>>>((const float4*)x, src, dst, out);
    }
    transform2_kernel<<<1024, 256, 0, stream>>>(x, W_rel, b_rel, W_root, out);
}

// Round 6
// 322.599 us; speedup vs baseline: 4.5005x; 1.1157x over previous
//
#include <hip/hip_runtime.h>

#define N_NODES 100000
#define N_EDGES 1600000
#define NFEAT 64
#define NCLASS 64
#define NPART 8
#define PART_SZ 12500   // N_NODES / NPART exactly

// ---------------------------------------------------------------------------
// CSR-build kernels (counting sort by destination)
// ---------------------------------------------------------------------------
__global__ void zero_int_kernel(int* __restrict__ p, int n) {
    int i = blockIdx.x * blockDim.x + threadIdx.x;
    int stride = gridDim.x * blockDim.x;
    for (; i < n; i += stride) p[i] = 0;
}

__global__ void hist_kernel(const int* __restrict__ dst, int* __restrict__ deg) {
    int e = blockIdx.x * blockDim.x + threadIdx.x;
    int stride = gridDim.x * blockDim.x;
    for (; e < N_EDGES; e += stride) atomicAdd(&deg[dst[e]], 1);
}

// ---- multi-block exclusive scan of deg[0..N_NODES) -> offs, cursor ----
#define SCAN_CHUNK 512
#define SCAN_NBLK ((N_NODES + SCAN_CHUNK - 1) / SCAN_CHUNK)   // 196

__global__ __launch_bounds__(256) void scan1_kernel(const int* __restrict__ deg,
                                                    int* __restrict__ blocksum) {
    __shared__ int part[256];
    int b = blockIdx.x, t = threadIdx.x;
    int i0 = b * SCAN_CHUNK + t * 2;
    int s = 0;
    if (i0 < N_NODES)     s += deg[i0];
    if (i0 + 1 < N_NODES) s += deg[i0 + 1];
    part[t] = s;
    __syncthreads();
    for (int off = 128; off > 0; off >>= 1) {
        if (t < off) part[t] += part[t + off];
        __syncthreads();
    }
    if (t == 0) blocksum[b] = part[0];
}

__global__ __launch_bounds__(256) void scan2_kernel(const int* __restrict__ blocksum,
                                                    int* __restrict__ blockoff,
                                                    int* __restrict__ offs) {
    __shared__ int part[256];
    int t = threadIdx.x;
    int v = (t < SCAN_NBLK) ? blocksum[t] : 0;
    part[t] = v;
    __syncthreads();
    for (int off = 1; off < 256; off <<= 1) {
        int u = (t >= off) ? part[t - off] : 0;
        __syncthreads();
        part[t] += u;
        __syncthreads();
    }
    if (t < SCAN_NBLK) blockoff[t] = part[t] - v;   // exclusive
    if (t == 0) offs[N_NODES] = part[255];
}

__global__ __launch_bounds__(256) void scan3_kernel(const int* __restrict__ deg,
                                                    const int* __restrict__ blockoff,
                                                    int* __restrict__ offs,
                                                    int* __restrict__ cursor) {
    __shared__ int part[256];
    int b = blockIdx.x, t = threadIdx.x;
    int i0 = b * SCAN_CHUNK + t * 2;
    int d0 = (i0 < N_NODES) ? deg[i0] : 0;
    int d1 = (i0 + 1 < N_NODES) ? deg[i0 + 1] : 0;
    int p = d0 + d1;
    part[t] = p;
    __syncthreads();
    for (int off = 1; off < 256; off <<= 1) {
        int u = (t >= off) ? part[t - off] : 0;
        __syncthreads();
        part[t] += u;
        __syncthreads();
    }
    int base = blockoff[b] + part[t] - p;
    if (i0 < N_NODES)     { offs[i0] = base;           cursor[i0] = base; }
    if (i0 + 1 < N_NODES) { offs[i0 + 1] = base + d0;  cursor[i0 + 1] = base + d0; }
}

// ---------------------------------------------------------------------------
// Partitioned fill: block-group (blockIdx&7) handles dst-part (dst/12500)==g.
// ---------------------------------------------------------------------------
__global__ __launch_bounds__(256) void fill_part_kernel(const int* __restrict__ src,
                                                        const int* __restrict__ dst,
                                                        int* __restrict__ cursor,
                                                        int* __restrict__ srclist) {
    const int g  = blockIdx.x & (NPART - 1);
    const int gb = blockIdx.x >> 3;
    const int nb = gridDim.x >> 3;
    int e = gb * blockDim.x + threadIdx.x;
    const int stride = nb * blockDim.x;
    for (; e < N_EDGES; e += stride) {
        int d = dst[e];
        int s = src[e];
        if (d / PART_SZ == g) {
            int p = atomicAdd(&cursor[d], 1);
            srclist[p] = s;
        }
    }
}

// ---------------------------------------------------------------------------
// Gather aggregation: one 64-lane wave per node, lane = feature.
// ---------------------------------------------------------------------------
__global__ __launch_bounds__(256) void gather_kernel(const float* __restrict__ x,
                                                     const int* __restrict__ offs,
                                                     const int* __restrict__ srclist,
                                                     float* __restrict__ agg) {
    int wave = (blockIdx.x * blockDim.x + threadIdx.x) >> 6;
    int lane = threadIdx.x & 63;
    if (wave >= N_NODES) return;
    int beg = offs[wave];
    int end = offs[wave + 1];
    float acc = 0.f;
    int j = beg;
    for (; j + 4 <= end; j += 4) {
        int s0 = srclist[j + 0];
        int s1 = srclist[j + 1];
        int s2 = srclist[j + 2];
        int s3 = srclist[j + 3];
        float v0 = x[s0 * 64 + lane];
        float v1 = x[s1 * 64 + lane];
        float v2 = x[s2 * 64 + lane];
        float v3 = x[s3 * 64 + lane];
        acc += v0; acc += v1; acc += v2; acc += v3;
    }
    for (; j < end; ++j) acc += x[srclist[j] * 64 + lane];
    agg[wave * 64 + lane] = acc;
}

// ---------------------------------------------------------------------------
// Fallback path: atomic scatter (proven round 2)
// ---------------------------------------------------------------------------
__global__ void zero_kernel(float4* __restrict__ p, int n4) {
    int i = blockIdx.x * blockDim.x + threadIdx.x;
    int stride = gridDim.x * blockDim.x;
    for (; i < n4; i += stride) p[i] = make_float4(0.f, 0.f, 0.f, 0.f);
}

__global__ void scatter_kernel(const float4* __restrict__ x4,
                               const int* __restrict__ src,
                               const int* __restrict__ dst,
                               float* __restrict__ agg) {
    int idx = blockIdx.x * blockDim.x + threadIdx.x;
    const int total = N_EDGES * 16;
    int stride = gridDim.x * blockDim.x;
    for (; idx < total; idx += stride) {
        int e = idx >> 4;
        int q = idx & 15;
        int s = src[e];
        int d = dst[e];
        float4 v = x4[s * 16 + q];
        float* base = agg + d * 64 + q * 4;
        unsafeAtomicAdd(base + 0, v.x);
        unsafeAtomicAdd(base + 1, v.y);
        unsafeAtomicAdd(base + 2, v.z);
        unsafeAtomicAdd(base + 3, v.w);
    }
}

// ---------------------------------------------------------------------------
// Transform v3: lane = class; weights pinned in VGPRs.
// __launch_bounds__(256,1): regalloc budget up to 512 VGPR (no occupancy-
// driven rematerialization). asm "+v" makes each loaded weight opaque so the
// compiler CANNOT re-load it from global inside the node loop (round-5 bug:
// VGPR_Count=88 proved weights were being re-fetched per node).
// ---------------------------------------------------------------------------
__global__ __launch_bounds__(256, 1) void transform3_kernel(
    const float* __restrict__ x,
    const float* __restrict__ W_rel,    // [class][feat] row-major
    const float* __restrict__ b_rel,
    const float* __restrict__ W_root,
    float* __restrict__ agg_out) {      // in: agg, out: result (in-place)
    const int lane = threadIdx.x & 63;

    float4 wr[16], wo[16];
    const float4* Wr4 = (const float4*)W_rel;
    const float4* Wo4 = (const float4*)W_root;
    #pragma unroll
    for (int i = 0; i < 16; ++i) {
        float4 a = Wr4[lane * 16 + i];      // W_rel[lane][4i..4i+3]
        float4 b = Wo4[lane * 16 + i];
        asm volatile("" : "+v"(a.x), "+v"(a.y), "+v"(a.z), "+v"(a.w));
        asm volatile("" : "+v"(b.x), "+v"(b.y), "+v"(b.z), "+v"(b.w));
        wr[i] = a;
        wo[i] = b;
    }
    const float bias = b_rel[lane];

    int gwave = (blockIdx.x * blockDim.x + threadIdx.x) >> 6;
    int nwaves = (gridDim.x * blockDim.x) >> 6;

    for (int node = gwave; node < N_NODES; node += nwaves) {
        const float4* ar4 = (const float4*)(agg_out + (size_t)node * 64);
        const float4* xr4 = (const float4*)(x + (size_t)node * 64);
        float acc = bias;
        #pragma unroll      // FULL unroll: static wr[i]/wo[i] indices (rule #20)
        for (int i = 0; i < 16; ++i) {
            float4 a = ar4[i];              // wave-uniform -> line broadcast
            float4 v = xr4[i];
            acc += a.x * wr[i].x + a.y * wr[i].y + a.z * wr[i].z + a.w * wr[i].w;
            acc += v.x * wo[i].x + v.y * wo[i].y + v.z * wo[i].z + v.w * wo[i].w;
        }
        agg_out[(size_t)node * 64 + lane] = fmaxf(acc, 0.f);
    }
}

extern "C" void kernel_launch(void* const* d_in, const int* in_sizes, int n_in,
                              void* d_out, int out_size, void* d_ws, size_t ws_size,
                              hipStream_t stream) {
    const float* x      = (const float*)d_in[0];
    const int*   adj    = (const int*)d_in[1];   // delivered as int32 [2][N_EDGES]
    const float* W_rel  = (const float*)d_in[2];
    const float* b_rel  = (const float*)d_in[3];
    const float* W_root = (const float*)d_in[4];
    float*       out    = (float*)d_out;

    const int* src = adj;
    const int* dst = adj + N_EDGES;

    const size_t NPAD = 100032;                 // >= N_NODES+1, multiple of 64
    const size_t BPAD = 256;
    const size_t ws_needed = (3 * NPAD + 2 * BPAD + (size_t)N_EDGES) * sizeof(int);

    if (ws_size >= ws_needed) {
        int* deg      = (int*)d_ws;
        int* offs     = deg + NPAD;
        int* cursor   = offs + NPAD;
        int* blocksum = cursor + NPAD;
        int* blockoff = blocksum + BPAD;
        int* srclist  = blockoff + BPAD;

        zero_int_kernel<<<128, 256, 0, stream>>>(deg, N_NODES);
        hist_kernel<<<2048, 256, 0, stream>>>(dst, deg);
        scan1_kernel<<<SCAN_NBLK, 256, 0, stream>>>(deg, blocksum);
        scan2_kernel<<<1, 256, 0, stream>>>(blocksum, blockoff, offs);
        scan3_kernel<<<SCAN_NBLK, 256, 0, stream>>>(deg, blockoff, offs, cursor);
        fill_part_kernel<<<2048, 256, 0, stream>>>(src, dst, cursor, srclist);
        gather_kernel<<<(N_NODES * 64 + 255) / 256, 256, 0, stream>>>(x, offs, srclist, out);
    } else {
        zero_kernel<<<2048, 256, 0, stream>>>((float4*)out, (N_NODES * NFEAT) / 4);
        scatter_kernel<<<4096, 256, 0, stream>>>((const float4*)x, src, dst, out);
    }
    transform3_kernel<<<1024, 256, 0, stream>>>(x, W_rel, b_rel, W_root, out);
}

// Round 7
// 239.031 us; speedup vs baseline: 6.0740x; 1.3496x over previous
//
#include <hip/hip_runtime.h>

#define N_NODES 100000
#define N_EDGES 1600000
#define NFEAT 64
#define NCLASS 64
#define NPART 8
#define PART_SZ 12500   // N_NODES / NPART exactly
#define NGROUPS (N_NODES / 16)   // 6250 16-node MFMA groups

typedef __attribute__((ext_vector_type(8))) short bf16x8;   // 8 bf16 = 4 VGPRs
typedef __attribute__((ext_vector_type(4))) float f32x4;

__device__ inline unsigned short f2bf(float f) {   // round-to-nearest-even
    union { float f; unsigned u; } v; v.f = f;
    unsigned u = v.u + 0x7fffu + ((v.u >> 16) & 1u);
    return (unsigned short)(u >> 16);
}

// ---------------------------------------------------------------------------
// CSR-build kernels (counting sort by destination)
// ---------------------------------------------------------------------------
__global__ void zero_int_kernel(int* __restrict__ p, int n) {
    int i = blockIdx.x * blockDim.x + threadIdx.x;
    int stride = gridDim.x * blockDim.x;
    for (; i < n; i += stride) p[i] = 0;
}

__global__ void hist_kernel(const int* __restrict__ dst, int* __restrict__ deg) {
    int e = blockIdx.x * blockDim.x + threadIdx.x;
    int stride = gridDim.x * blockDim.x;
    for (; e < N_EDGES; e += stride) atomicAdd(&deg[dst[e]], 1);
}

#define SCAN_CHUNK 512
#define SCAN_NBLK ((N_NODES + SCAN_CHUNK - 1) / SCAN_CHUNK)   // 196

__global__ __launch_bounds__(256) void scan1_kernel(const int* __restrict__ deg,
                                                    int* __restrict__ blocksum) {
    __shared__ int part[256];
    int b = blockIdx.x, t = threadIdx.x;
    int i0 = b * SCAN_CHUNK + t * 2;
    int s = 0;
    if (i0 < N_NODES)     s += deg[i0];
    if (i0 + 1 < N_NODES) s += deg[i0 + 1];
    part[t] = s;
    __syncthreads();
    for (int off = 128; off > 0; off >>= 1) {
        if (t < off) part[t] += part[t + off];
        __syncthreads();
    }
    if (t == 0) blocksum[b] = part[0];
}

__global__ __launch_bounds__(256) void scan2_kernel(const int* __restrict__ blocksum,
                                                    int* __restrict__ blockoff,
                                                    int* __restrict__ offs) {
    __shared__ int part[256];
    int t = threadIdx.x;
    int v = (t < SCAN_NBLK) ? blocksum[t] : 0;
    part[t] = v;
    __syncthreads();
    for (int off = 1; off < 256; off <<= 1) {
        int u = (t >= off) ? part[t - off] : 0;
        __syncthreads();
        part[t] += u;
        __syncthreads();
    }
    if (t < SCAN_NBLK) blockoff[t] = part[t] - v;   // exclusive
    if (t == 0) offs[N_NODES] = part[255];
}

__global__ __launch_bounds__(256) void scan3_kernel(const int* __restrict__ deg,
                                                    const int* __restrict__ blockoff,
                                                    int* __restrict__ offs,
                                                    int* __restrict__ cursor) {
    __shared__ int part[256];
    int b = blockIdx.x, t = threadIdx.x;
    int i0 = b * SCAN_CHUNK + t * 2;
    int d0 = (i0 < N_NODES) ? deg[i0] : 0;
    int d1 = (i0 + 1 < N_NODES) ? deg[i0 + 1] : 0;
    int p = d0 + d1;
    part[t] = p;
    __syncthreads();
    for (int off = 1; off < 256; off <<= 1) {
        int u = (t >= off) ? part[t - off] : 0;
        __syncthreads();
        part[t] += u;
        __syncthreads();
    }
    int base = blockoff[b] + part[t] - p;
    if (i0 < N_NODES)     { offs[i0] = base;           cursor[i0] = base; }
    if (i0 + 1 < N_NODES) { offs[i0 + 1] = base + d0;  cursor[i0 + 1] = base + d0; }
}

// ---------------------------------------------------------------------------
// Partitioned fill: block-group (blockIdx&7) handles dst-part (dst/12500)==g.
// ---------------------------------------------------------------------------
__global__ __launch_bounds__(256) void fill_part_kernel(const int* __restrict__ src,
                                                        const int* __restrict__ dst,
                                                        int* __restrict__ cursor,
                                                        int* __restrict__ srclist) {
    const int g  = blockIdx.x & (NPART - 1);
    const int gb = blockIdx.x >> 3;
    const int nb = gridDim.x >> 3;
    int e = gb * blockDim.x + threadIdx.x;
    const int stride = nb * blockDim.x;
    for (; e < N_EDGES; e += stride) {
        int d = dst[e];
        int s = src[e];
        if (d / PART_SZ == g) {
            int p = atomicAdd(&cursor[d], 1);
            srclist[p] = s;
        }
    }
}

// ---------------------------------------------------------------------------
// Gather aggregation + bf16 A-matrix emit: one wave per node, lane = feature.
// A[node][0:64]  = bf16(sum_{j in nbrs} x[j][lane])
// A[node][64:128]= bf16(x[node][lane])
// ---------------------------------------------------------------------------
__global__ __launch_bounds__(256) void gather_bf16_kernel(
    const float* __restrict__ x,
    const int* __restrict__ offs,
    const int* __restrict__ srclist,
    unsigned short* __restrict__ A) {
    int wave = (blockIdx.x * blockDim.x + threadIdx.x) >> 6;
    int lane = threadIdx.x & 63;
    if (wave >= N_NODES) return;
    int beg = offs[wave];
    int end = offs[wave + 1];
    float acc = 0.f;
    int j = beg;
    for (; j + 4 <= end; j += 4) {
        int s0 = srclist[j + 0];
        int s1 = srclist[j + 1];
        int s2 = srclist[j + 2];
        int s3 = srclist[j + 3];
        float v0 = x[s0 * 64 + lane];
        float v1 = x[s1 * 64 + lane];
        float v2 = x[s2 * 64 + lane];
        float v3 = x[s3 * 64 + lane];
        acc += v0; acc += v1; acc += v2; acc += v3;
    }
    for (; j < end; ++j) acc += x[srclist[j] * 64 + lane];
    float xv = x[(size_t)wave * 64 + lane];
    A[(size_t)wave * 128 + lane]      = f2bf(acc);
    A[(size_t)wave * 128 + 64 + lane] = f2bf(xv);
}

// ---------------------------------------------------------------------------
// Weight prep: Wcat[c][0:64]=bf16(W_rel[c][:]), Wcat[c][64:128]=bf16(W_root[c][:])
// ---------------------------------------------------------------------------
__global__ __launch_bounds__(256) void wprep_kernel(const float* __restrict__ W_rel,
                                                    const float* __restrict__ W_root,
                                                    unsigned short* __restrict__ Wcat) {
    int i = blockIdx.x * blockDim.x + threadIdx.x;   // 8192 total
    if (i >= NCLASS * 128) return;
    int c = i >> 7, k = i & 127;
    float v = (k < 64) ? W_rel[c * 64 + k] : W_root[c * 64 + (k - 64)];
    Wcat[i] = f2bf(v);
}

// ---------------------------------------------------------------------------
// MFMA transform: out[n][c] = relu( sum_k A[n][k] * Wcat[c][k] + b[c] )
// One wave per 16-node group. B (all of W, 64 VGPRs) loaded once per wave.
// Fragment layouts (m89-verified):
//   A-op: row = lane&15, k = (lane>>4)*8 + e   -> 16B contiguous loads
//   B-op: col = lane&15, k = (lane>>4)*8 + e   (B[k][c] = Wcat[c][k])
//   C/D : col = lane&15, row = (lane>>4)*4 + reg
// ---------------------------------------------------------------------------
__global__ __launch_bounds__(256, 2) void transform_mfma_kernel(
    const unsigned short* __restrict__ A,     // [N][128] bf16
    const unsigned short* __restrict__ Wcat,  // [64][128] bf16
    const float* __restrict__ b_rel,
    float* __restrict__ out) {
    const int lane = threadIdx.x & 63;
    const int lr = lane & 15;      // tile row/col selector
    const int lh = lane >> 4;      // k-quarter selector

    bf16x8 bfr[4][4];              // [class-group][k-step]
    #pragma unroll
    for (int cg = 0; cg < 4; ++cg)
        #pragma unroll
        for (int kk = 0; kk < 4; ++kk)
            bfr[cg][kk] = *(const bf16x8*)(Wcat + (cg * 16 + lr) * 128 + kk * 32 + lh * 8);

    float bias[4];
    #pragma unroll
    for (int cg = 0; cg < 4; ++cg) bias[cg] = b_rel[cg * 16 + lr];

    int wid = (blockIdx.x * blockDim.x + threadIdx.x) >> 6;
    int nw  = (gridDim.x * blockDim.x) >> 6;

    for (int g = wid; g < NGROUPS; g += nw) {
        const unsigned short* Ab = A + (size_t)(g * 16 + lr) * 128;
        bf16x8 afr[4];
        #pragma unroll
        for (int kk = 0; kk < 4; ++kk)
            afr[kk] = *(const bf16x8*)(Ab + kk * 32 + lh * 8);
        #pragma unroll
        for (int cg = 0; cg < 4; ++cg) {
            f32x4 acc = {0.f, 0.f, 0.f, 0.f};
            #pragma unroll
            for (int kk = 0; kk < 4; ++kk)
                acc = __builtin_amdgcn_mfma_f32_16x16x32_bf16(afr[kk], bfr[cg][kk], acc, 0, 0, 0);
            #pragma unroll
            for (int r = 0; r < 4; ++r)
                out[(size_t)(g * 16 + lh * 4 + r) * 64 + cg * 16 + lr] =
                    fmaxf(acc[r] + bias[cg], 0.f);
        }
    }
}

// ---------------------------------------------------------------------------
// Fallback path: atomic scatter + fp32 transform (proven rounds 2/6)
// ---------------------------------------------------------------------------
__global__ void zero_kernel(float4* __restrict__ p, int n4) {
    int i = blockIdx.x * blockDim.x + threadIdx.x;
    int stride = gridDim.x * blockDim.x;
    for (; i < n4; i += stride) p[i] = make_float4(0.f, 0.f, 0.f, 0.f);
}

__global__ void scatter_kernel(const float4* __restrict__ x4,
                               const int* __restrict__ src,
                               const int* __restrict__ dst,
                               float* __restrict__ agg) {
    int idx = blockIdx.x * blockDim.x + threadIdx.x;
    const int total = N_EDGES * 16;
    int stride = gridDim.x * blockDim.x;
    for (; idx < total; idx += stride) {
        int e = idx >> 4;
        int q = idx & 15;
        int s = src[e];
        int d = dst[e];
        float4 v = x4[s * 16 + q];
        float* base = agg + d * 64 + q * 4;
        unsafeAtomicAdd(base + 0, v.x);
        unsafeAtomicAdd(base + 1, v.y);
        unsafeAtomicAdd(base + 2, v.z);
        unsafeAtomicAdd(base + 3, v.w);
    }
}

__global__ __launch_bounds__(256, 1) void transform3_kernel(
    const float* __restrict__ x,
    const float* __restrict__ W_rel,
    const float* __restrict__ b_rel,
    const float* __restrict__ W_root,
    float* __restrict__ agg_out) {
    const int lane = threadIdx.x & 63;
    float4 wr[16], wo[16];
    const float4* Wr4 = (const float4*)W_rel;
    const float4* Wo4 = (const float4*)W_root;
    #pragma unroll
    for (int i = 0; i < 16; ++i) {
        float4 a = Wr4[lane * 16 + i];
        float4 b = Wo4[lane * 16 + i];
        asm volatile("" : "+v"(a.x), "+v"(a.y), "+v"(a.z), "+v"(a.w));
        asm volatile("" : "+v"(b.x), "+v"(b.y), "+v"(b.z), "+v"(b.w));
        wr[i] = a;
        wo[i] = b;
    }
    const float bias = b_rel[lane];
    int gwave = (blockIdx.x * blockDim.x + threadIdx.x) >> 6;
    int nwaves = (gridDim.x * blockDim.x) >> 6;
    for (int node = gwave; node < N_NODES; node += nwaves) {
        const float4* ar4 = (const float4*)(agg_out + (size_t)node * 64);
        const float4* xr4 = (const float4*)(x + (size_t)node * 64);
        float acc = bias;
        #pragma unroll
        for (int i = 0; i < 16; ++i) {
            float4 a = ar4[i];
            float4 v = xr4[i];
            acc += a.x * wr[i].x + a.y * wr[i].y + a.z * wr[i].z + a.w * wr[i].w;
            acc += v.x * wo[i].x + v.y * wo[i].y + v.z * wo[i].z + v.w * wo[i].w;
        }
        agg_out[(size_t)node * 64 + lane] = fmaxf(acc, 0.f);
    }
}

extern "C" void kernel_launch(void* const* d_in, const int* in_sizes, int n_in,
                              void* d_out, int out_size, void* d_ws, size_t ws_size,
                              hipStream_t stream) {
    const float* x      = (const float*)d_in[0];
    const int*   adj    = (const int*)d_in[1];   // delivered as int32 [2][N_EDGES]
    const float* W_rel  = (const float*)d_in[2];
    const float* b_rel  = (const float*)d_in[3];
    const float* W_root = (const float*)d_in[4];
    float*       out    = (float*)d_out;

    const int* src = adj;
    const int* dst = adj + N_EDGES;

    // workspace layout: int region | Wcat bf16 | A bf16
    const size_t NPAD = 100032;                 // >= N_NODES+1, multiple of 64
    const size_t BPAD = 256;
    const size_t n_ints = 3 * NPAD + 2 * BPAD + (size_t)N_EDGES;
    const size_t wcat_elems = (size_t)NCLASS * 128;
    const size_t a_elems = (size_t)N_NODES * 128;
    const size_t ws_needed = n_ints * sizeof(int) + 128 +
                             (wcat_elems + a_elems) * sizeof(unsigned short);

    if (ws_size >= ws_needed) {
        int* deg      = (int*)d_ws;
        int* offs     = deg + NPAD;
        int* cursor   = offs + NPAD;
        int* blocksum = cursor + NPAD;
        int* blockoff = blocksum + BPAD;
        int* srclist  = blockoff + BPAD;
        size_t bf_base = ((n_ints * sizeof(int)) + 127) & ~(size_t)127;
        unsigned short* Wcat = (unsigned short*)((char*)d_ws + bf_base);
        unsigned short* A    = Wcat + wcat_elems;

        zero_int_kernel<<<128, 256, 0, stream>>>(deg, N_NODES);
        hist_kernel<<<2048, 256, 0, stream>>>(dst, deg);
        scan1_kernel<<<SCAN_NBLK, 256, 0, stream>>>(deg, blocksum);
        scan2_kernel<<<1, 256, 0, stream>>>(blocksum, blockoff, offs);
        scan3_kernel<<<SCAN_NBLK, 256, 0, stream>>>(deg, blockoff, offs, cursor);
        fill_part_kernel<<<2048, 256, 0, stream>>>(src, dst, cursor, srclist);
        wprep_kernel<<<(NCLASS * 128 + 255) / 256, 256, 0, stream>>>(W_rel, W_root, Wcat);
        gather_bf16_kernel<<<(N_NODES * 64 + 255) / 256, 256, 0, stream>>>(x, offs, srclist, A);
        transform_mfma_kernel<<<1024, 256, 0, stream>>>(A, Wcat, b_rel, out);
    } else {
        zero_kernel<<<2048, 256, 0, stream>>>((float4*)out, (N_NODES * NFEAT) / 4);
        scatter_kernel<<<4096, 256, 0, stream>>>((const float4*)x, src, dst, out);
        transform3_kernel<<<1024, 256, 0, stream>>>(x, W_rel, b_rel, W_root, out);
    }
}

// Round 8
// 236.854 us; speedup vs baseline: 6.1298x; 1.0092x over previous
//
#include <hip/hip_runtime.h>

#define N_NODES 100000
#define N_EDGES 1600000
#define NFEAT 64
#define NCLASS 64
#define NPART 8
#define PART_SZ 12500   // N_NODES / NPART exactly
#define NGROUPS (N_NODES / 16)   // 6250 16-node MFMA groups

typedef __attribute__((ext_vector_type(8))) short bf16x8;   // 8 bf16 = 4 VGPRs
typedef __attribute__((ext_vector_type(4))) float f32x4;

__device__ inline unsigned short f2bf(float f) {   // round-to-nearest-even
    union { float f; unsigned u; } v; v.f = f;
    unsigned u = v.u + 0x7fffu + ((v.u >> 16) & 1u);
    return (unsigned short)(u >> 16);
}
__device__ inline float bf2f(unsigned short s) {
    union { unsigned u; float f; } v; v.u = ((unsigned)s) << 16;
    return v.f;
}

// ---------------------------------------------------------------------------
// CSR-build kernels (counting sort by destination)
// ---------------------------------------------------------------------------
__global__ void zero_int_kernel(int* __restrict__ p, int n) {
    int i = blockIdx.x * blockDim.x + threadIdx.x;
    int stride = gridDim.x * blockDim.x;
    for (; i < n; i += stride) p[i] = 0;
}

__global__ void hist_kernel(const int* __restrict__ dst, int* __restrict__ deg) {
    int e = blockIdx.x * blockDim.x + threadIdx.x;
    int stride = gridDim.x * blockDim.x;
    for (; e < N_EDGES; e += stride) atomicAdd(&deg[dst[e]], 1);
}

#define SCAN_CHUNK 512
#define SCAN_NBLK ((N_NODES + SCAN_CHUNK - 1) / SCAN_CHUNK)   // 196

__global__ __launch_bounds__(256) void scan1_kernel(const int* __restrict__ deg,
                                                    int* __restrict__ blocksum) {
    __shared__ int part[256];
    int b = blockIdx.x, t = threadIdx.x;
    int i0 = b * SCAN_CHUNK + t * 2;
    int s = 0;
    if (i0 < N_NODES)     s += deg[i0];
    if (i0 + 1 < N_NODES) s += deg[i0 + 1];
    part[t] = s;
    __syncthreads();
    for (int off = 128; off > 0; off >>= 1) {
        if (t < off) part[t] += part[t + off];
        __syncthreads();
    }
    if (t == 0) blocksum[b] = part[0];
}

__global__ __launch_bounds__(256) void scan2_kernel(const int* __restrict__ blocksum,
                                                    int* __restrict__ blockoff,
                                                    int* __restrict__ offs) {
    __shared__ int part[256];
    int t = threadIdx.x;
    int v = (t < SCAN_NBLK) ? blocksum[t] : 0;
    part[t] = v;
    __syncthreads();
    for (int off = 1; off < 256; off <<= 1) {
        int u = (t >= off) ? part[t - off] : 0;
        __syncthreads();
        part[t] += u;
        __syncthreads();
    }
    if (t < SCAN_NBLK) blockoff[t] = part[t] - v;   // exclusive
    if (t == 0) offs[N_NODES] = part[255];
}

__global__ __launch_bounds__(256) void scan3_kernel(const int* __restrict__ deg,
                                                    const int* __restrict__ blockoff,
                                                    int* __restrict__ offs,
                                                    int* __restrict__ cursor) {
    __shared__ int part[256];
    int b = blockIdx.x, t = threadIdx.x;
    int i0 = b * SCAN_CHUNK + t * 2;
    int d0 = (i0 < N_NODES) ? deg[i0] : 0;
    int d1 = (i0 + 1 < N_NODES) ? deg[i0 + 1] : 0;
    int p = d0 + d1;
    part[t] = p;
    __syncthreads();
    for (int off = 1; off < 256; off <<= 1) {
        int u = (t >= off) ? part[t - off] : 0;
        __syncthreads();
        part[t] += u;
        __syncthreads();
    }
    int base = blockoff[b] + part[t] - p;
    if (i0 < N_NODES)     { offs[i0] = base;           cursor[i0] = base; }
    if (i0 + 1 < N_NODES) { offs[i0 + 1] = base + d0;  cursor[i0 + 1] = base + d0; }
}

// ---------------------------------------------------------------------------
// Partitioned fill: block-group (blockIdx&7) handles dst-part (dst/12500)==g.
// ---------------------------------------------------------------------------
__global__ __launch_bounds__(256) void fill_part_kernel(const int* __restrict__ src,
                                                        const int* __restrict__ dst,
                                                        int* __restrict__ cursor,
                                                        int* __restrict__ srclist) {
    const int g  = blockIdx.x & (NPART - 1);
    const int gb = blockIdx.x >> 3;
    const int nb = gridDim.x >> 3;
    int e = gb * blockDim.x + threadIdx.x;
    const int stride = nb * blockDim.x;
    for (; e < N_EDGES; e += stride) {
        int d = dst[e];
        int s = src[e];
        if (d / PART_SZ == g) {
            int p = atomicAdd(&cursor[d], 1);
            srclist[p] = s;
        }
    }
}

// ---------------------------------------------------------------------------
// x -> bf16 cast (one streaming pass; gather then moves half the bytes)
// ---------------------------------------------------------------------------
__global__ void x2bf_kernel(const float4* __restrict__ x4,
                            ushort4* __restrict__ xb4) {
    int i = blockIdx.x * blockDim.x + threadIdx.x;
    const int n4 = N_NODES * NFEAT / 4;
    int stride = gridDim.x * blockDim.x;
    for (; i < n4; i += stride) {
        float4 v = x4[i];
        ushort4 o;
        o.x = f2bf(v.x); o.y = f2bf(v.y); o.z = f2bf(v.z); o.w = f2bf(v.w);
        xb4[i] = o;
    }
}

// ---------------------------------------------------------------------------
// Gather aggregation over bf16 rows: one wave per node, lane = feature.
// agg_bf[node][lane] = bf16( sum_{j in nbrs} bf2f(x_bf[src_j][lane]) )
// 128B coalesced row reads (half the fp32 traffic).
// ---------------------------------------------------------------------------
__global__ __launch_bounds__(256) void gather_bf_kernel(
    const unsigned short* __restrict__ x_bf,
    const int* __restrict__ offs,
    const int* __restrict__ srclist,
    unsigned short* __restrict__ agg_bf) {
    int wave = (blockIdx.x * blockDim.x + threadIdx.x) >> 6;
    int lane = threadIdx.x & 63;
    if (wave >= N_NODES) return;
    int beg = offs[wave];
    int end = offs[wave + 1];
    float acc = 0.f;
    int j = beg;
    for (; j + 4 <= end; j += 4) {
        int s0 = srclist[j + 0];
        int s1 = srclist[j + 1];
        int s2 = srclist[j + 2];
        int s3 = srclist[j + 3];
        unsigned short v0 = x_bf[(size_t)s0 * 64 + lane];
        unsigned short v1 = x_bf[(size_t)s1 * 64 + lane];
        unsigned short v2 = x_bf[(size_t)s2 * 64 + lane];
        unsigned short v3 = x_bf[(size_t)s3 * 64 + lane];
        acc += bf2f(v0); acc += bf2f(v1); acc += bf2f(v2); acc += bf2f(v3);
    }
    for (; j < end; ++j) acc += bf2f(x_bf[(size_t)srclist[j] * 64 + lane]);
    agg_bf[(size_t)wave * 64 + lane] = f2bf(acc);
}

// ---------------------------------------------------------------------------
// Weight prep: Wcat[c][0:64]=bf16(W_rel[c][:]), Wcat[c][64:128]=bf16(W_root[c][:])
// ---------------------------------------------------------------------------
__global__ __launch_bounds__(256) void wprep_kernel(const float* __restrict__ W_rel,
                                                    const float* __restrict__ W_root,
                                                    unsigned short* __restrict__ Wcat) {
    int i = blockIdx.x * blockDim.x + threadIdx.x;   // 8192 total
    if (i >= NCLASS * 128) return;
    int c = i >> 7, k = i & 127;
    float v = (k < 64) ? W_rel[c * 64 + k] : W_root[c * 64 + (k - 64)];
    Wcat[i] = f2bf(v);
}

// ---------------------------------------------------------------------------
// MFMA transform v2: out[n][c] = relu( agg[n]·W_rel[c] + x[n]·W_root[c] + b[c] )
// A-fragments: kk=0,1 from agg_bf row (K 0..63), kk=2,3 from x_bf row (K 64..127).
// Fragment layouts (m89-verified): A row=lane&15, k=(lane>>4)*8+e;
// B col=lane&15 same k; D col=lane&15, row=(lane>>4)*4+reg.
// ---------------------------------------------------------------------------
__global__ __launch_bounds__(256, 2) void transform_mfma_kernel(
    const unsigned short* __restrict__ agg_bf,  // [N][64] bf16
    const unsigned short* __restrict__ x_bf,    // [N][64] bf16
    const unsigned short* __restrict__ Wcat,    // [64][128] bf16
    const float* __restrict__ b_rel,
    float* __restrict__ out) {
    const int lane = threadIdx.x & 63;
    const int lr = lane & 15;      // tile row/col selector
    const int lh = lane >> 4;      // k-quarter selector

    bf16x8 bfr[4][4];              // [class-group][k-step over K=128]
    #pragma unroll
    for (int cg = 0; cg < 4; ++cg)
        #pragma unroll
        for (int kk = 0; kk < 4; ++kk)
            bfr[cg][kk] = *(const bf16x8*)(Wcat + (cg * 16 + lr) * 128 + kk * 32 + lh * 8);

    float bias[4];
    #pragma unroll
    for (int cg = 0; cg < 4; ++cg) bias[cg] = b_rel[cg * 16 + lr];

    int wid = (blockIdx.x * blockDim.x + threadIdx.x) >> 6;
    int nw  = (gridDim.x * blockDim.x) >> 6;

    for (int g = wid; g < NGROUPS; g += nw) {
        const unsigned short* Aa = agg_bf + (size_t)(g * 16 + lr) * 64;
        const unsigned short* Ax = x_bf   + (size_t)(g * 16 + lr) * 64;
        bf16x8 afr[4];
        #pragma unroll
        for (int kk = 0; kk < 2; ++kk) {
            afr[kk]     = *(const bf16x8*)(Aa + kk * 32 + lh * 8);
            afr[kk + 2] = *(const bf16x8*)(Ax + kk * 32 + lh * 8);
        }
        #pragma unroll
        for (int cg = 0; cg < 4; ++cg) {
            f32x4 acc = {0.f, 0.f, 0.f, 0.f};
            #pragma unroll
            for (int kk = 0; kk < 4; ++kk)
                acc = __builtin_amdgcn_mfma_f32_16x16x32_bf16(afr[kk], bfr[cg][kk], acc, 0, 0, 0);
            #pragma unroll
            for (int r = 0; r < 4; ++r)
                out[(size_t)(g * 16 + lh * 4 + r) * 64 + cg * 16 + lr] =
                    fmaxf(acc[r] + bias[cg], 0.f);
        }
    }
}

// ---------------------------------------------------------------------------
// Fallback path: atomic scatter + fp32 transform (proven rounds 2/6)
// ---------------------------------------------------------------------------
__global__ void zero_kernel(float4* __restrict__ p, int n4) {
    int i = blockIdx.x * blockDim.x + threadIdx.x;
    int stride = gridDim.x * blockDim.x;
    for (; i < n4; i += stride) p[i] = make_float4(0.f, 0.f, 0.f, 0.f);
}

__global__ void scatter_kernel(const float4* __restrict__ x4,
                               const int* __restrict__ src,
                               const int* __restrict__ dst,
                               float* __restrict__ agg) {
    int idx = blockIdx.x * blockDim.x + threadIdx.x;
    const int total = N_EDGES * 16;
    int stride = gridDim.x * blockDim.x;
    for (; idx < total; idx += stride) {
        int e = idx >> 4;
        int q = idx & 15;
        int s = src[e];
        int d = dst[e];
        float4 v = x4[s * 16 + q];
        float* base = agg + d * 64 + q * 4;
        unsafeAtomicAdd(base + 0, v.x);
        unsafeAtomicAdd(base + 1, v.y);
        unsafeAtomicAdd(base + 2, v.z);
        unsafeAtomicAdd(base + 3, v.w);
    }
}

__global__ __launch_bounds__(256, 1) void transform3_kernel(
    const float* __restrict__ x,
    const float* __restrict__ W_rel,
    const float* __restrict__ b_rel,
    const float* __restrict__ W_root,
    float* __restrict__ agg_out) {
    const int lane = threadIdx.x & 63;
    float4 wr[16], wo[16];
    const float4* Wr4 = (const float4*)W_rel;
    const float4* Wo4 = (const float4*)W_root;
    #pragma unroll
    for (int i = 0; i < 16; ++i) {
        float4 a = Wr4[lane * 16 + i];
        float4 b = Wo4[lane * 16 + i];
        asm volatile("" : "+v"(a.x), "+v"(a.y), "+v"(a.z), "+v"(a.w));
        asm volatile("" : "+v"(b.x), "+v"(b.y), "+v"(b.z), "+v"(b.w));
        wr[i] = a;
        wo[i] = b;
    }
    const float bias = b_rel[lane];
    int gwave = (blockIdx.x * blockDim.x + threadIdx.x) >> 6;
    int nwaves = (gridDim.x * blockDim.x) >> 6;
    for (int node = gwave; node < N_NODES; node += nwaves) {
        const float4* ar4 = (const float4*)(agg_out + (size_t)node * 64);
        const float4* xr4 = (const float4*)(x + (size_t)node * 64);
        float acc = bias;
        #pragma unroll
        for (int i = 0; i < 16; ++i) {
            float4 a = ar4[i];
            float4 v = xr4[i];
            acc += a.x * wr[i].x + a.y * wr[i].y + a.z * wr[i].z + a.w * wr[i].w;
            acc += v.x * wo[i].x + v.y * wo[i].y + v.z * wo[i].z + v.w * wo[i].w;
        }
        agg_out[(size_t)node * 64 + lane] = fmaxf(acc, 0.f);
    }
}

extern "C" void kernel_launch(void* const* d_in, const int* in_sizes, int n_in,
                              void* d_out, int out_size, void* d_ws, size_t ws_size,
                              hipStream_t stream) {
    const float* x      = (const float*)d_in[0];
    const int*   adj    = (const int*)d_in[1];   // delivered as int32 [2][N_EDGES]
    const float* W_rel  = (const float*)d_in[2];
    const float* b_rel  = (const float*)d_in[3];
    const float* W_root = (const float*)d_in[4];
    float*       out    = (float*)d_out;

    const int* src = adj;
    const int* dst = adj + N_EDGES;

    // workspace layout: int region | Wcat bf16 | agg_bf | x_bf
    const size_t NPAD = 100032;                 // >= N_NODES+1, multiple of 64
    const size_t BPAD = 256;
    const size_t n_ints = 3 * NPAD + 2 * BPAD + (size_t)N_EDGES;
    const size_t wcat_elems = (size_t)NCLASS * 128;
    const size_t row_elems  = (size_t)N_NODES * 64;
    const size_t ws_needed = n_ints * sizeof(int) + 128 +
                             (wcat_elems + 2 * row_elems) * sizeof(unsigned short);

    if (ws_size >= ws_needed) {
        int* deg      = (int*)d_ws;
        int* offs     = deg + NPAD;
        int* cursor   = offs + NPAD;
        int* blocksum = cursor + NPAD;
        int* blockoff = blocksum + BPAD;
        int* srclist  = blockoff + BPAD;
        size_t bf_base = ((n_ints * sizeof(int)) + 127) & ~(size_t)127;
        unsigned short* Wcat   = (unsigned short*)((char*)d_ws + bf_base);
        unsigned short* agg_bf = Wcat + wcat_elems;
        unsigned short* x_bf   = agg_bf + row_elems;

        zero_int_kernel<<<128, 256, 0, stream>>>(deg, N_NODES);
        hist_kernel<<<2048, 256, 0, stream>>>(dst, deg);
        scan1_kernel<<<SCAN_NBLK, 256, 0, stream>>>(deg, blocksum);
        scan2_kernel<<<1, 256, 0, stream>>>(blocksum, blockoff, offs);
        scan3_kernel<<<SCAN_NBLK, 256, 0, stream>>>(deg, blockoff, offs, cursor);
        fill_part_kernel<<<2048, 256, 0, stream>>>(src, dst, cursor, srclist);
        x2bf_kernel<<<2048, 256, 0, stream>>>((const float4*)x, (ushort4*)x_bf);
        wprep_kernel<<<(NCLASS * 128 + 255) / 256, 256, 0, stream>>>(W_rel, W_root, Wcat);
        gather_bf_kernel<<<(N_NODES * 64 + 255) / 256, 256, 0, stream>>>(x_bf, offs, srclist, agg_bf);
        transform_mfma_kernel<<<1024, 256, 0, stream>>>(agg_bf, x_bf, Wcat, b_rel, out);
    } else {
        zero_kernel<<<2048, 256, 0, stream>>>((float4*)out, (N_NODES * NFEAT) / 4);
        scatter_kernel<<<4096, 256, 0, stream>>>((const float4*)x, src, dst, out);
        transform3_kernel<<<1024, 256, 0, stream>>>(x, W_rel, b_rel, W_root, out);
    }
}